// Round 5
// baseline (127.494 us; speedup 1.0000x reference)
//
#include <hip/hip_runtime.h>

// 4-level mask loss, two kernels.
// K1: blocks 0..11 rasterize box-union (3000 (level,row,word32) tasks, register
//     bitmask only); blocks 12..2047 grid-stride nontemporal f32x4 sum of the 4
//     pyramids (90.9 MB, read-once -> nt loads), 4-way unrolled, f64 block partials.
// K2: one block reduces partials+counts -> loss.
//
// Lessons: R1 — no same-line atomics (8192 f64 atomics ~120us). R1 — no
// dynamically-indexed private arrays (scratch demotion). R3 — no per-block
// __threadfence()+atomic completion (device fence = per-XCD L2 wb/inv, ~60us at
// this grid); kernel-boundary release/acquire is cheap and sufficient.

#define NBLK 2048
#define RAST_BLOCKS 12
#define SUM_BLOCKS (NBLK - RAST_BLOCKS)
#define CNT_OFF (NBLK * 4 * 8)

typedef float f32x4 __attribute__((ext_vector_type(4)));

__device__ __forceinline__ double wave_red_d(double v) {
#pragma unroll
  for (int off = 32; off > 0; off >>= 1) v += __shfl_down(v, off, 64);
  return v;
}
__device__ __forceinline__ int wave_red_i(int v) {
#pragma unroll
  for (int off = 32; off > 0; off >>= 1) v += __shfl_down(v, off, 64);
  return v;
}
__device__ __forceinline__ double hsum4(f32x4 v) {
  return (double)((v.x + v.y) + (v.z + v.w));
}

__global__ __launch_bounds__(256) void work_kernel(
    const f32x4* __restrict__ p0, const f32x4* __restrict__ p1,
    const f32x4* __restrict__ p2, const f32x4* __restrict__ p3,
    int n0, int n1, int n2, int n3,
    const float* __restrict__ label, int nboxes,
    const int* __restrict__ dimx_p, const int* __restrict__ dimy_p,
    double* __restrict__ partials) {
  int* counts = (int*)((char*)partials + CNT_OFF);
  const int tid = threadIdx.x;
  const int blk = blockIdx.x;
  __shared__ double shd[4][4];
  __shared__ int shi[4][4];

  if (blk < RAST_BLOCKS) {
    // ---------------- raster path ----------------
    __shared__ int sx1[4][256], sx2[4][256], sy1[4][256], sy2[4][256];
    const double imx = (double)dimx_p[0];
    const double imy = (double)dimy_p[0];
    const int nb = nboxes < 256 ? nboxes : 256;
    for (int idx = tid; idx < 4 * nb; idx += 256) {
      const int lvl = idx / nb;
      const int j = idx - lvl * nb;
      const int w = (lvl == 0) ? 334 : (lvl == 1) ? 167 : (lvl == 2) ? 84 : 42;
      const int h = (lvl == 0) ? 200 : (lvl == 1) ? 100 : (lvl == 2) ? 50 : 25;
      const float sx = (float)((double)w / imx);  // jnp: f64 div -> f32 weak mul
      const float sy = (float)((double)h / imy);
      float b0 = label[j * 4 + 0], b1 = label[j * 4 + 1];
      float b2 = label[j * 4 + 2], b3 = label[j * 4 + 3];
      int x1 = (int)fminf(fmaxf(rintf(b0 * sx), 0.0f), (float)(w - 1));
      int y1 = (int)fminf(fmaxf(rintf(b1 * sy), 0.0f), (float)(h - 1));
      int x2 = (int)fminf(fmaxf(rintf(b2 * sx), 0.0f), (float)w);
      int y2 = (int)fminf(fmaxf(rintf(b3 * sy), 0.0f), (float)h);
      bool valid = (x2 > x1) && (y2 > y1) && (x1 + x2 < w) && (y1 + y2 < h);
      sx1[lvl][j] = x1; sx2[lvl][j] = x2;
      sy1[lvl][j] = valid ? y1 : 0x7fffffff;  // never covers any row
      sy2[lvl][j] = y2;
    }
    __syncthreads();
    const int t = blk * 256 + tid;  // 3000 tasks over 3072 threads
    int lvl = 0, r = 0, wd = 0;
    const bool has = (t < 3000);
    if (has) {
      if (t < 2200)      { lvl = 0; unsigned u = t;        r = u / 11; wd = u - r * 11; }
      else if (t < 2800) { lvl = 1; unsigned u = t - 2200; r = u / 6;  wd = u - r * 6; }
      else if (t < 2950) { lvl = 2; unsigned u = t - 2800; r = u / 3;  wd = u - r * 3; }
      else               { lvl = 3; unsigned u = t - 2950; r = u >> 1; wd = u & 1; }
    }
    const int col0 = wd << 5;
    unsigned m = 0;
    if (has) {
      for (int j = 0; j < nb; j++) {
        const int y1 = sy1[lvl][j], y2 = sy2[lvl][j];
        const int a = sx1[lvl][j], b = sx2[lvl][j];
        const bool inrow = (r >= y1) & (r < y2);
        int lo = a - col0; lo = lo > 0 ? lo : 0;
        int hi = b - col0; hi = hi < 32 ? hi : 32;
        if (inrow && hi > lo) {
          unsigned mh = (hi >= 32) ? 0xffffffffu : ((1u << (hi & 31)) - 1u);
          m |= mh & (0xffffffffu << (lo & 31));
        }
      }
    }
    const int pc = __popc(m);
    int c0 = (lvl == 0) ? pc : 0, c1 = (lvl == 1) ? pc : 0;
    int c2 = (lvl == 2) ? pc : 0, c3 = (lvl == 3) ? pc : 0;
    c0 = wave_red_i(c0); c1 = wave_red_i(c1); c2 = wave_red_i(c2); c3 = wave_red_i(c3);
    const int wid = tid >> 6;
    if ((tid & 63) == 0) { shi[wid][0] = c0; shi[wid][1] = c1; shi[wid][2] = c2; shi[wid][3] = c3; }
    __syncthreads();
    if (tid == 0) {
      int* dst = &counts[blk * 4];
#pragma unroll
      for (int l = 0; l < 4; l++) dst[l] = shi[0][l] + shi[1][l] + shi[2][l] + shi[3][l];
    }
  } else {
    // ---------------- sum path (nontemporal: read-once streams) ----------------
    const int gid = (blk - RAST_BLOCKS) * 256 + tid;
    const int stride = SUM_BLOCKS * 256;
    double a0 = 0.0, a0b = 0.0, a1 = 0.0, a1b = 0.0, a2 = 0.0, a3 = 0.0;
    int i = gid;
    for (; i + 3 * stride < n0; i += 4 * stride) {  // 4 independent loads in flight
      f32x4 v0 = __builtin_nontemporal_load(&p0[i]);
      f32x4 v1 = __builtin_nontemporal_load(&p0[i + stride]);
      f32x4 v2 = __builtin_nontemporal_load(&p0[i + 2 * stride]);
      f32x4 v3 = __builtin_nontemporal_load(&p0[i + 3 * stride]);
      a0  += hsum4(v0) + hsum4(v1);
      a0b += hsum4(v2) + hsum4(v3);
    }
    for (; i < n0; i += stride) a0 += hsum4(__builtin_nontemporal_load(&p0[i]));
    a0 += a0b;
    i = gid;
    for (; i + stride < n1; i += 2 * stride) {
      f32x4 v0 = __builtin_nontemporal_load(&p1[i]);
      f32x4 v1 = __builtin_nontemporal_load(&p1[i + stride]);
      a1 += hsum4(v0);
      a1b += hsum4(v1);
    }
    for (; i < n1; i += stride) a1 += hsum4(__builtin_nontemporal_load(&p1[i]));
    a1 += a1b;
    for (i = gid; i < n2; i += stride) a2 += hsum4(__builtin_nontemporal_load(&p2[i]));
    for (i = gid; i < n3; i += stride) a3 += hsum4(__builtin_nontemporal_load(&p3[i]));
    a0 = wave_red_d(a0); a1 = wave_red_d(a1); a2 = wave_red_d(a2); a3 = wave_red_d(a3);
    const int wid = tid >> 6;
    if ((tid & 63) == 0) { shd[wid][0] = a0; shd[wid][1] = a1; shd[wid][2] = a2; shd[wid][3] = a3; }
    __syncthreads();
    if (tid == 0) {
      double* dst = &partials[blk * 4];
#pragma unroll
      for (int l = 0; l < 4; l++) dst[l] = shd[0][l] + shd[1][l] + shd[2][l] + shd[3][l];
    }
  }
}

__global__ __launch_bounds__(256) void finish_kernel(
    const double* __restrict__ partials, float* __restrict__ out) {
  const int* counts = (const int*)((const char*)partials + CNT_OFF);
  const int tid = threadIdx.x;
  double s0 = 0.0, s1 = 0.0, s2 = 0.0, s3 = 0.0;
  // each thread reads one block's 32B of partials per iter (2x double2, contiguous)
  typedef double f64x2 __attribute__((ext_vector_type(2)));
  const f64x2* p2v = (const f64x2*)partials;
  for (int b = RAST_BLOCKS + tid; b < NBLK; b += 256) {
    f64x2 lo = p2v[b * 2 + 0];
    f64x2 hi = p2v[b * 2 + 1];
    s0 += lo.x; s1 += lo.y; s2 += hi.x; s3 += hi.y;
  }
  int c0 = 0, c1 = 0, c2 = 0, c3 = 0;
  if (tid < RAST_BLOCKS) {
    c0 = counts[tid * 4 + 0]; c1 = counts[tid * 4 + 1];
    c2 = counts[tid * 4 + 2]; c3 = counts[tid * 4 + 3];
  }
  s0 = wave_red_d(s0); s1 = wave_red_d(s1); s2 = wave_red_d(s2); s3 = wave_red_d(s3);
  c0 = wave_red_i(c0); c1 = wave_red_i(c1); c2 = wave_red_i(c2); c3 = wave_red_i(c3);
  __shared__ double shd[4][4];
  __shared__ int shi[4][4];
  const int wid = tid >> 6;
  if ((tid & 63) == 0) {
    shd[wid][0] = s0; shd[wid][1] = s1; shd[wid][2] = s2; shd[wid][3] = s3;
    shi[wid][0] = c0; shi[wid][1] = c1; shi[wid][2] = c2; shi[wid][3] = c3;
  }
  __syncthreads();
  if (tid == 0) {
    const double HH[4] = {200.0, 100.0, 50.0, 25.0};
    const double WW[4] = {334.0, 167.0, 84.0, 42.0};
    double loss = 0.0;
#pragma unroll
    for (int l = 0; l < 4; l++) {
      double s = shd[0][l] + shd[1][l] + shd[2][l] + shd[3][l];
      double c = (double)(shi[0][l] + shi[1][l] + shi[2][l] + shi[3][l]);
      double tn = 256.0 * HH[l] * WW[l];
      double d = (s - c) / tn;
      loss += d * d;
    }
    out[0] = (float)(loss * 0.25);
  }
}

extern "C" void kernel_launch(void* const* d_in, const int* in_sizes, int n_in,
                              void* d_out, int out_size, void* d_ws, size_t ws_size,
                              hipStream_t stream) {
  const f32x4* p0 = (const f32x4*)d_in[0];
  const f32x4* p1 = (const f32x4*)d_in[1];
  const f32x4* p2 = (const f32x4*)d_in[2];
  const f32x4* p3 = (const f32x4*)d_in[3];
  const float* label = (const float*)d_in[4];
  const int* dimx = (const int*)d_in[5];
  const int* dimy = (const int*)d_in[6];

  const int n0 = in_sizes[0] / 4;
  const int n1 = in_sizes[1] / 4;
  const int n2 = in_sizes[2] / 4;
  const int n3 = in_sizes[3] / 4;
  const int nboxes = in_sizes[4] / 4;

  work_kernel<<<NBLK, 256, 0, stream>>>(
      p0, p1, p2, p3, n0, n1, n2, n3, label, nboxes, dimx, dimy, (double*)d_ws);
  finish_kernel<<<1, 256, 0, stream>>>((const double*)d_ws, (float*)d_out);
}

// Round 6
// 119.276 us; speedup vs baseline: 1.0689x; 1.0689x over previous
//
#include <hip/hip_runtime.h>

// 4-level mask loss, two kernels.
// K1: blocks 0..11 rasterize box-union (3000 (level,row,word32) tasks, register
//     bitmask only); blocks 12..2047 grid-stride f32x4 sum of the 4 pyramids
//     (90.9 MB), 4-way unrolled, f64 block partials. PLAIN loads — inputs are
//     LLC-warm from the harness restore copy; R5 showed NT loads forfeit those
//     hits (+45 MB HBM fetch = +7us).
// K2: one block reduces partials+counts -> loss.
//
// Lessons: R1 — no same-line atomics (8192 f64 atomics ~120us). R1 — no
// dynamically-indexed private arrays (scratch demotion). R3 — no per-block
// __threadfence()+atomic completion (device fence = per-XCD L2 wb/inv, ~60us at
// this grid); kernel-boundary release/acquire is cheap and sufficient.
// R5 — no nontemporal loads on LLC-warm data.

#define NBLK 2048
#define RAST_BLOCKS 12
#define SUM_BLOCKS (NBLK - RAST_BLOCKS)
#define CNT_OFF (NBLK * 4 * 8)

typedef float f32x4 __attribute__((ext_vector_type(4)));

__device__ __forceinline__ double wave_red_d(double v) {
#pragma unroll
  for (int off = 32; off > 0; off >>= 1) v += __shfl_down(v, off, 64);
  return v;
}
__device__ __forceinline__ int wave_red_i(int v) {
#pragma unroll
  for (int off = 32; off > 0; off >>= 1) v += __shfl_down(v, off, 64);
  return v;
}
__device__ __forceinline__ double hsum4(f32x4 v) {
  return (double)((v.x + v.y) + (v.z + v.w));
}

__global__ __launch_bounds__(256) void work_kernel(
    const f32x4* __restrict__ p0, const f32x4* __restrict__ p1,
    const f32x4* __restrict__ p2, const f32x4* __restrict__ p3,
    int n0, int n1, int n2, int n3,
    const float* __restrict__ label, int nboxes,
    const int* __restrict__ dimx_p, const int* __restrict__ dimy_p,
    double* __restrict__ partials) {
  int* counts = (int*)((char*)partials + CNT_OFF);
  const int tid = threadIdx.x;
  const int blk = blockIdx.x;
  __shared__ double shd[4][4];
  __shared__ int shi[4][4];

  if (blk < RAST_BLOCKS) {
    // ---------------- raster path ----------------
    __shared__ int sx1[4][256], sx2[4][256], sy1[4][256], sy2[4][256];
    const double imx = (double)dimx_p[0];
    const double imy = (double)dimy_p[0];
    const int nb = nboxes < 256 ? nboxes : 256;
    for (int idx = tid; idx < 4 * nb; idx += 256) {
      const int lvl = idx / nb;
      const int j = idx - lvl * nb;
      const int w = (lvl == 0) ? 334 : (lvl == 1) ? 167 : (lvl == 2) ? 84 : 42;
      const int h = (lvl == 0) ? 200 : (lvl == 1) ? 100 : (lvl == 2) ? 50 : 25;
      const float sx = (float)((double)w / imx);  // jnp: f64 div -> f32 weak mul
      const float sy = (float)((double)h / imy);
      float b0 = label[j * 4 + 0], b1 = label[j * 4 + 1];
      float b2 = label[j * 4 + 2], b3 = label[j * 4 + 3];
      int x1 = (int)fminf(fmaxf(rintf(b0 * sx), 0.0f), (float)(w - 1));
      int y1 = (int)fminf(fmaxf(rintf(b1 * sy), 0.0f), (float)(h - 1));
      int x2 = (int)fminf(fmaxf(rintf(b2 * sx), 0.0f), (float)w);
      int y2 = (int)fminf(fmaxf(rintf(b3 * sy), 0.0f), (float)h);
      bool valid = (x2 > x1) && (y2 > y1) && (x1 + x2 < w) && (y1 + y2 < h);
      sx1[lvl][j] = x1; sx2[lvl][j] = x2;
      sy1[lvl][j] = valid ? y1 : 0x7fffffff;  // never covers any row
      sy2[lvl][j] = y2;
    }
    __syncthreads();
    const int t = blk * 256 + tid;  // 3000 tasks over 3072 threads
    int lvl = 0, r = 0, wd = 0;
    const bool has = (t < 3000);
    if (has) {
      if (t < 2200)      { lvl = 0; unsigned u = t;        r = u / 11; wd = u - r * 11; }
      else if (t < 2800) { lvl = 1; unsigned u = t - 2200; r = u / 6;  wd = u - r * 6; }
      else if (t < 2950) { lvl = 2; unsigned u = t - 2800; r = u / 3;  wd = u - r * 3; }
      else               { lvl = 3; unsigned u = t - 2950; r = u >> 1; wd = u & 1; }
    }
    const int col0 = wd << 5;
    unsigned m = 0;
    if (has) {
      for (int j = 0; j < nb; j++) {
        const int y1 = sy1[lvl][j], y2 = sy2[lvl][j];
        const int a = sx1[lvl][j], b = sx2[lvl][j];
        const bool inrow = (r >= y1) & (r < y2);
        int lo = a - col0; lo = lo > 0 ? lo : 0;
        int hi = b - col0; hi = hi < 32 ? hi : 32;
        if (inrow && hi > lo) {
          unsigned mh = (hi >= 32) ? 0xffffffffu : ((1u << (hi & 31)) - 1u);
          m |= mh & (0xffffffffu << (lo & 31));
        }
      }
    }
    const int pc = __popc(m);
    int c0 = (lvl == 0) ? pc : 0, c1 = (lvl == 1) ? pc : 0;
    int c2 = (lvl == 2) ? pc : 0, c3 = (lvl == 3) ? pc : 0;
    c0 = wave_red_i(c0); c1 = wave_red_i(c1); c2 = wave_red_i(c2); c3 = wave_red_i(c3);
    const int wid = tid >> 6;
    if ((tid & 63) == 0) { shi[wid][0] = c0; shi[wid][1] = c1; shi[wid][2] = c2; shi[wid][3] = c3; }
    __syncthreads();
    if (tid == 0) {
      int* dst = &counts[blk * 4];
#pragma unroll
      for (int l = 0; l < 4; l++) dst[l] = shi[0][l] + shi[1][l] + shi[2][l] + shi[3][l];
    }
  } else {
    // ---------------- sum path (plain loads: LLC-warm input) ----------------
    const int gid = (blk - RAST_BLOCKS) * 256 + tid;
    const int stride = SUM_BLOCKS * 256;
    double a0 = 0.0, a0b = 0.0, a1 = 0.0, a1b = 0.0, a2 = 0.0, a3 = 0.0;
    int i = gid;
    for (; i + 3 * stride < n0; i += 4 * stride) {  // 4 independent loads in flight
      f32x4 v0 = p0[i], v1 = p0[i + stride], v2 = p0[i + 2 * stride], v3 = p0[i + 3 * stride];
      a0  += hsum4(v0) + hsum4(v1);
      a0b += hsum4(v2) + hsum4(v3);
    }
    for (; i < n0; i += stride) a0 += hsum4(p0[i]);
    a0 += a0b;
    i = gid;
    for (; i + stride < n1; i += 2 * stride) {
      f32x4 v0 = p1[i], v1 = p1[i + stride];
      a1 += hsum4(v0);
      a1b += hsum4(v1);
    }
    for (; i < n1; i += stride) a1 += hsum4(p1[i]);
    a1 += a1b;
    for (i = gid; i < n2; i += stride) a2 += hsum4(p2[i]);
    for (i = gid; i < n3; i += stride) a3 += hsum4(p3[i]);
    a0 = wave_red_d(a0); a1 = wave_red_d(a1); a2 = wave_red_d(a2); a3 = wave_red_d(a3);
    const int wid = tid >> 6;
    if ((tid & 63) == 0) { shd[wid][0] = a0; shd[wid][1] = a1; shd[wid][2] = a2; shd[wid][3] = a3; }
    __syncthreads();
    if (tid == 0) {
      double* dst = &partials[blk * 4];
#pragma unroll
      for (int l = 0; l < 4; l++) dst[l] = shd[0][l] + shd[1][l] + shd[2][l] + shd[3][l];
    }
  }
}

__global__ __launch_bounds__(256) void finish_kernel(
    const double* __restrict__ partials, float* __restrict__ out) {
  const int* counts = (const int*)((const char*)partials + CNT_OFF);
  const int tid = threadIdx.x;
  double s0 = 0.0, s1 = 0.0, s2 = 0.0, s3 = 0.0;
  typedef double f64x2 __attribute__((ext_vector_type(2)));
  const f64x2* p2v = (const f64x2*)partials;
  for (int b = RAST_BLOCKS + tid; b < NBLK; b += 256) {
    f64x2 lo = p2v[b * 2 + 0];
    f64x2 hi = p2v[b * 2 + 1];
    s0 += lo.x; s1 += lo.y; s2 += hi.x; s3 += hi.y;
  }
  int c0 = 0, c1 = 0, c2 = 0, c3 = 0;
  if (tid < RAST_BLOCKS) {
    c0 = counts[tid * 4 + 0]; c1 = counts[tid * 4 + 1];
    c2 = counts[tid * 4 + 2]; c3 = counts[tid * 4 + 3];
  }
  s0 = wave_red_d(s0); s1 = wave_red_d(s1); s2 = wave_red_d(s2); s3 = wave_red_d(s3);
  c0 = wave_red_i(c0); c1 = wave_red_i(c1); c2 = wave_red_i(c2); c3 = wave_red_i(c3);
  __shared__ double shd[4][4];
  __shared__ int shi[4][4];
  const int wid = tid >> 6;
  if ((tid & 63) == 0) {
    shd[wid][0] = s0; shd[wid][1] = s1; shd[wid][2] = s2; shd[wid][3] = s3;
    shi[wid][0] = c0; shi[wid][1] = c1; shi[wid][2] = c2; shi[wid][3] = c3;
  }
  __syncthreads();
  if (tid == 0) {
    const double HH[4] = {200.0, 100.0, 50.0, 25.0};
    const double WW[4] = {334.0, 167.0, 84.0, 42.0};
    double loss = 0.0;
#pragma unroll
    for (int l = 0; l < 4; l++) {
      double s = shd[0][l] + shd[1][l] + shd[2][l] + shd[3][l];
      double c = (double)(shi[0][l] + shi[1][l] + shi[2][l] + shi[3][l]);
      double tn = 256.0 * HH[l] * WW[l];
      double d = (s - c) / tn;
      loss += d * d;
    }
    out[0] = (float)(loss * 0.25);
  }
}

extern "C" void kernel_launch(void* const* d_in, const int* in_sizes, int n_in,
                              void* d_out, int out_size, void* d_ws, size_t ws_size,
                              hipStream_t stream) {
  const f32x4* p0 = (const f32x4*)d_in[0];
  const f32x4* p1 = (const f32x4*)d_in[1];
  const f32x4* p2 = (const f32x4*)d_in[2];
  const f32x4* p3 = (const f32x4*)d_in[3];
  const float* label = (const float*)d_in[4];
  const int* dimx = (const int*)d_in[5];
  const int* dimy = (const int*)d_in[6];

  const int n0 = in_sizes[0] / 4;
  const int n1 = in_sizes[1] / 4;
  const int n2 = in_sizes[2] / 4;
  const int n3 = in_sizes[3] / 4;
  const int nboxes = in_sizes[4] / 4;

  work_kernel<<<NBLK, 256, 0, stream>>>(
      p0, p1, p2, p3, n0, n1, n2, n3, label, nboxes, dimx, dimy, (double*)d_ws);
  finish_kernel<<<1, 256, 0, stream>>>((const double*)d_ws, (float*)d_out);
}